// Round 4
// baseline (152.604 us; speedup 1.0000x reference)
//
#include <hip/hip_runtime.h>

// LocalAttention, MFMA bf16, round 11 = max occupancy via swapped-QK restructure.
// B=4, L=2048, H=16, E=D=64, window=64. fp32 in/out; bf16 MFMA; fp32 accumulate.
//
// r7-r10 series: duration tracks waves/CU (8->46us, 12->44, 16->41) and nothing
// else; every pipe <25% busy. LDS sets blocks/CU; VGPR pool ~512/SIMD means
// 8 waves/SIMD (32/CU) needs VGPR<=64 (r9 used 52). Saturating our HBM share
// needs ~9KB in flight per CU; 4 blocks x 40%-duty x ~3KB chunks = half that,
// matching measured 4.6 B/cy. 8 blocks -> saturation.
//
// Restructure to cut LDS 37.9KB -> 19.4KB (Vt only):
//   1. SWAPPED QK: c = mfma(K_frag, Q_frag) -> C = S^T. Lane (quad,col16)
//      holds S[key=16tt+4quad+r][query=col16]. With the PV key-slot bijection
//      key(8q+j) = 32ks + 16(j>>2) + 4q + (j&3), the softmaxed P packs
//      DIRECTLY into PV A-fragments in-register: no P LDS, no P barriers,
//      no shuffles. Softmax reduce = shfl_xor 16,32 only (keys live across
//      quads; query fixed per col16).
//   2. K direct from global per-tt fragment (no Ks LDS): 4x intra-block
//      re-read served by L1/L2 (K block working set 32KB), HBM unchanged.
//   3. LDS = Vt[64][152] bf16 = 19456 B -> 8 blocks/CU = 32 waves = FULL.
//      ONE barrier. launch_bounds(256,8) -> 64-VGPR cap.
// PV stays on verified mfma_f32_16x16x32_bf16: 3 K=32 steps x 4 dim-tiles;
// tail step has A-elems 4..7 = 0 and reads zeroed Vt cols 128..143.

#define B_ 4
#define L_ 2048
#define H_ 16
#define E_ 64
#define D_ 64
#define VT_STRIDE 152

typedef __attribute__((ext_vector_type(8))) short short8;
typedef __attribute__((ext_vector_type(4))) float f32x4;

__device__ __forceinline__ unsigned int f2bf(float x) {
  unsigned int b = __float_as_uint(x);
  b += 0x7fffu + ((b >> 16) & 1u);   // RNE to bf16
  return b >> 16;
}
__device__ __forceinline__ unsigned int pack2(float a, float b) {
  return f2bf(a) | (f2bf(b) << 16);
}
__device__ __forceinline__ short8 pack8(const f32x4& a, const f32x4& b) {
  union { short8 s; uint4 u; } r;
  r.u = make_uint4(pack2(a[0], a[1]), pack2(a[2], a[3]),
                   pack2(b[0], b[1]), pack2(b[2], b[3]));
  return r.s;
}
__device__ __forceinline__ int clampL(int k) {
  return k < 0 ? 0 : (k > (L_ - 1) ? (L_ - 1) : k);
}

__global__ __launch_bounds__(256, 8)
void local_attn_mfma(const float* __restrict__ qg,
                     const float* __restrict__ kg,
                     const float* __restrict__ vg,
                     float* __restrict__ og) {
  __shared__ __align__(16) unsigned short Vt[64 * VT_STRIDE];  // [dim][key_rel], 19456 B

  const int t = threadIdx.x;
  const int q0 = blockIdx.x * 64;
  const int h = blockIdx.y;
  const int b = blockIdx.z;
  const int kstart = q0 - 32;
  const int wave = t >> 6;
  const int lane = t & 63;
  const int col16 = lane & 15;
  const int quad = lane >> 4;

  // ---- V staging: 2 keys x 16-dim quarter per thread -> Vt transposed ----
  const int kp = t >> 2;               // key pair -> keys kstart+2kp, +2kp+1
  const int dq = t & 3;                // dim quarter: dims dq*16 .. +15
  f32x4 va[4], vc[4];
  {
    const int k0 = clampL(kstart + 2 * kp);
    const int k1 = clampL(kstart + 2 * kp + 1);
    const float* p0 = vg + ((size_t)(b * L_ + k0) * H_ + h) * D_ + dq * 16;
    const float* p1 = vg + ((size_t)(b * L_ + k1) * H_ + h) * D_ + dq * 16;
    #pragma unroll
    for (int i = 0; i < 4; ++i) va[i] = *(const f32x4*)(p0 + i * 4);
    #pragma unroll
    for (int i = 0; i < 4; ++i) vc[i] = *(const f32x4*)(p1 + i * 4);
  }

  // ---- Q fragment (B-operand of swapped QK): Q[q0+wave*16+col16][dims] ----
  short8 qa0, qa1;
  {
    const float* pq = qg + ((size_t)(b * L_ + q0 + wave * 16 + col16) * H_ + h) * E_ + quad * 8;
    f32x4 qf0 = *(const f32x4*)pq;
    f32x4 qf1 = *(const f32x4*)(pq + 4);
    f32x4 qf2 = *(const f32x4*)(pq + 32);
    f32x4 qf3 = *(const f32x4*)(pq + 36);
    qa0 = pack8(qf0, qf1);
    qa1 = pack8(qf2, qf3);
  }

  // ---- V pack -> LDS (bf16), zero-pad key cols 128..143 ----
  #pragma unroll
  for (int i = 0; i < 4; ++i)
    #pragma unroll
    for (int j = 0; j < 4; ++j) {
      int d = dq * 16 + i * 4 + j;
      *(unsigned int*)&Vt[d * VT_STRIDE + 2 * kp] = pack2(va[i][j], vc[i][j]);
    }
  *(uint2*)&Vt[(t >> 2) * VT_STRIDE + 128 + (t & 3) * 4] = make_uint2(0u, 0u);

  __syncthreads();   // the ONLY barrier

  // ---- QK swapped: acc = S^T tile. A = K-frag direct from global ----
  // A[m=key(col16)][e=quad*8+j]; B = qa (Q^T by fragment symmetry).
  // C: lane holds S[key = wave*16 + tt*16 + quad*4 + r][query = col16].
  f32x4 acc[5];
  #pragma unroll
  for (int tt = 0; tt < 5; ++tt) {
    const int key = clampL(kstart + wave * 16 + tt * 16 + col16);
    const float* pk = kg + ((size_t)(b * L_ + key) * H_ + h) * E_ + quad * 8;
    f32x4 k0 = *(const f32x4*)pk;
    f32x4 k1 = *(const f32x4*)(pk + 4);
    f32x4 k2 = *(const f32x4*)(pk + 32);
    f32x4 k3 = *(const f32x4*)(pk + 36);
    short8 kb0 = pack8(k0, k1);
    short8 kb1 = pack8(k2, k3);
    f32x4 c = {0.f, 0.f, 0.f, 0.f};
    c = __builtin_amdgcn_mfma_f32_16x16x32_bf16(kb0, qa0, c, 0, 0, 0);
    c = __builtin_amdgcn_mfma_f32_16x16x32_bf16(kb1, qa1, c, 0, 0, 0);
    acc[tt] = c;
  }

  // ---- Mask + softmax. Query = col16 (fixed per lane); keys spread over
  //      (tt, quad, r). Cross-lane reduce = quads only: shfl_xor 16, 32. ----
  float mx = -1e30f;
  #pragma unroll
  for (int tt = 0; tt < 5; ++tt)
    #pragma unroll
    for (int r = 0; r < 4; ++r) {
      const int k_loc = tt * 16 + quad * 4 + r;          // key rel to wave band
      const int gkey = kstart + wave * 16 + k_loc;       // global key
      const bool ok = (k_loc >= col16) && (k_loc < col16 + 64) &&
                      (gkey >= 0) && (gkey < L_);
      const float v = ok ? acc[tt][r] * 0.125f : -1e30f; // scale = 1/sqrt(64)
      acc[tt][r] = v;
      mx = fmaxf(mx, v);
    }
  mx = fmaxf(mx, __shfl_xor(mx, 16));
  mx = fmaxf(mx, __shfl_xor(mx, 32));
  float s = 0.f;
  #pragma unroll
  for (int tt = 0; tt < 5; ++tt)
    #pragma unroll
    for (int r = 0; r < 4; ++r) {
      const float e = __expf(acc[tt][r] - mx);
      acc[tt][r] = e;
      s += e;
    }
  s += __shfl_xor(s, 16);
  s += __shfl_xor(s, 32);
  const float inv = 1.0f / s;          // >= 32 valid keys -> s >= 1

  // ---- P -> PV A-frags IN REGISTER (lane-local by construction).
  //      Key-slot bijection: elem j of pa[ks] = P[col16][32ks+16(j>>2)+4quad+(j&3)]
  //      = acc[2ks + (j>>2)][j&3]. Tail frag: elems 4..7 = 0. ----
  short8 pa[3];
  {
    union { short8 s8; uint4 u4; } w;
    w.u4 = make_uint4(pack2(acc[0][0] * inv, acc[0][1] * inv),
                      pack2(acc[0][2] * inv, acc[0][3] * inv),
                      pack2(acc[1][0] * inv, acc[1][1] * inv),
                      pack2(acc[1][2] * inv, acc[1][3] * inv));
    pa[0] = w.s8;
    w.u4 = make_uint4(pack2(acc[2][0] * inv, acc[2][1] * inv),
                      pack2(acc[2][2] * inv, acc[2][3] * inv),
                      pack2(acc[3][0] * inv, acc[3][1] * inv),
                      pack2(acc[3][2] * inv, acc[3][3] * inv));
    pa[1] = w.s8;
    w.u4 = make_uint4(pack2(acc[4][0] * inv, acc[4][1] * inv),
                      pack2(acc[4][2] * inv, acc[4][3] * inv), 0u, 0u);
    pa[2] = w.s8;
  }

  // ---- PV: per dim-tile nt, 3 K=32 steps. B elem j = V[key(quad*8+j)][dim]:
  //      two uint2 (4 consecutive keys each) at cols base+quad*4 and +16. ----
  f32x4 oacc[4];
  #pragma unroll
  for (int nt = 0; nt < 4; ++nt) oacc[nt] = (f32x4){0.f, 0.f, 0.f, 0.f};
  #pragma unroll
  for (int nt = 0; nt < 4; ++nt) {
    const int rowb = (nt * 16 + col16) * VT_STRIDE;
    #pragma unroll
    for (int ks = 0; ks < 3; ++ks) {
      union { short8 s8; uint2 u2[2]; } vb;
      vb.u2[0] = *(const uint2*)&Vt[rowb + wave * 16 + ks * 32 + quad * 4];
      vb.u2[1] = *(const uint2*)&Vt[rowb + wave * 16 + ks * 32 + 16 + quad * 4];
      oacc[nt] = __builtin_amdgcn_mfma_f32_16x16x32_bf16(pa[ks], vb.s8, oacc[nt], 0, 0, 0);
    }
  }

  // ---- Store O (fp32). C: row = quad*4+r (query), col = col16 (dim) ----
  #pragma unroll
  for (int r = 0; r < 4; ++r) {
    const int q = q0 + wave * 16 + quad * 4 + r;
    float* orow = og + ((size_t)(b * L_ + q) * H_ + h) * D_;
    #pragma unroll
    for (int nt = 0; nt < 4; ++nt)
      orow[nt * 16 + col16] = oacc[nt][r];
  }
}

extern "C" void kernel_launch(void* const* d_in, const int* in_sizes, int n_in,
                              void* d_out, int out_size, void* d_ws, size_t ws_size,
                              hipStream_t stream) {
  const float* q = (const float*)d_in[0];
  const float* k = (const float*)d_in[1];
  const float* v = (const float*)d_in[2];
  float* o = (float*)d_out;
  dim3 grid(L_ / 64, H_, B_);
  local_attn_mfma<<<grid, dim3(256), 0, stream>>>(q, k, v, o);
}

// Round 5
// 136.683 us; speedup vs baseline: 1.1165x; 1.1165x over previous
//
#include <hip/hip_runtime.h>

// LocalAttention, MFMA bf16, round 12 = zero-VGPR K staging via global_load_lds.
// B=4, L=2048, H=16, E=D=64, window=64. fp32 in/out; bf16 MFMA; fp32 accumulate.
//
// r7-r11 series conclusion: the compiler schedules register-destined loads for
// the launch_bounds occupancy target -- at high targets it minimizes VGPRs
// (r11: 32!) and serializes every load into ~700cy round trips; wave lifetime
// is 95% vmcnt wait. Occupancy alone regressed (r11: 45% occ, 53us). The only
// load type it cannot serialize is global_load_lds: no register destination,
// nothing dependent until the barrier.
//
//   1. K staged fp32 via 8x global_load_lds(16B) -> dense LDS [128][64] f32,
//      one 32KB zero-VGPR burst per block, single wait at the barrier.
//      LDS dest must be linear (wave-uniform base + lane*16), so bank-
//      decorrelation is done by PRE-SWIZZLING the global source chunk:
//      slot (row,c) holds global chunk c^(row&15); QK reads chunk g at
//      slot g^(row&15). 16-way stride-256B conflict -> ~4-way.
//   2. Swapped QK (r11, verified): c = mfma(K_frag, Q_frag) -> S^T; softmaxed
//      P packs directly into PV A-frags in-register; no P LDS, no P barriers;
//      softmax reduce = shfl_xor 16,32. K frags now read from LDS (fp32 ->
//      bf16 pack in reg), NOT global -- removing r11's in-loop latency.
//   3. V register-staged -> transposed bf16 Vt (as r8); V+Q loads sit in the
//      entry region where launch_bounds(256,3) gives ~170 free VGPRs (r10
//      proved the compiler batches with that budget).
// LDS = 32768 (Ks32) + 19456 (Vt) = 52224 B -> 3 blocks/CU. ONE barrier.

#define B_ 4
#define L_ 2048
#define H_ 16
#define E_ 64
#define D_ 64
#define VT_STRIDE 152

typedef __attribute__((ext_vector_type(8))) short short8;
typedef __attribute__((ext_vector_type(4))) float f32x4;

__device__ __forceinline__ unsigned int f2bf(float x) {
  unsigned int b = __float_as_uint(x);
  b += 0x7fffu + ((b >> 16) & 1u);   // RNE to bf16
  return b >> 16;
}
__device__ __forceinline__ unsigned int pack2(float a, float b) {
  return f2bf(a) | (f2bf(b) << 16);
}
__device__ __forceinline__ short8 pack8(const f32x4& a, const f32x4& b) {
  union { short8 s; uint4 u; } r;
  r.u = make_uint4(pack2(a[0], a[1]), pack2(a[2], a[3]),
                   pack2(b[0], b[1]), pack2(b[2], b[3]));
  return r.s;
}
__device__ __forceinline__ int clampL(int k) {
  return k < 0 ? 0 : (k > (L_ - 1) ? (L_ - 1) : k);
}

__global__ __launch_bounds__(256, 3)
void local_attn_mfma(const float* __restrict__ qg,
                     const float* __restrict__ kg,
                     const float* __restrict__ vg,
                     float* __restrict__ og) {
  __shared__ __align__(16) float Ks32[128 * 64];               // 32768 B, gload_lds dest
  __shared__ __align__(16) unsigned short Vt[64 * VT_STRIDE];  // 19456 B, [dim][key_rel]

  const int t = threadIdx.x;
  const int q0 = blockIdx.x * 64;
  const int h = blockIdx.y;
  const int b = blockIdx.z;
  const int kstart = q0 - 32;
  const int wave = t >> 6;
  const int lane = t & 63;
  const int col16 = lane & 15;
  const int quad = lane >> 4;

  // ---- V + Q register loads first (their vmcnt waits must not drain K) ----
  const int kp = t >> 2;               // key pair -> keys kstart+2kp, +2kp+1
  const int dq = t & 3;                // dim quarter: dims dq*16 .. +15
  f32x4 va[4], vc[4];
  {
    const int k0 = clampL(kstart + 2 * kp);
    const int k1 = clampL(kstart + 2 * kp + 1);
    const float* p0 = vg + ((size_t)(b * L_ + k0) * H_ + h) * D_ + dq * 16;
    const float* p1 = vg + ((size_t)(b * L_ + k1) * H_ + h) * D_ + dq * 16;
    #pragma unroll
    for (int i = 0; i < 4; ++i) va[i] = *(const f32x4*)(p0 + i * 4);
    #pragma unroll
    for (int i = 0; i < 4; ++i) vc[i] = *(const f32x4*)(p1 + i * 4);
  }
  f32x4 qf0, qf1, qf2, qf3;
  {
    const float* pq = qg + ((size_t)(b * L_ + q0 + wave * 16 + col16) * H_ + h) * E_ + quad * 8;
    qf0 = *(const f32x4*)pq;
    qf1 = *(const f32x4*)(pq + 4);
    qf2 = *(const f32x4*)(pq + 32);
    qf3 = *(const f32x4*)(pq + 36);
  }

  // ---- K staging: 8x global_load_lds, zero VGPRs, source chunk-swizzled.
  //      cid = row*16 + ch (16B chunks); LDS slot cid holds global chunk
  //      ch ^ (row & 15) of K row (clamped key kstart+row). ----
  #pragma unroll
  for (int it = 0; it < 8; ++it) {
    const int cid = t + it * 256;
    const int row = cid >> 4, ch = cid & 15;
    const int chs = ch ^ (row & 15);
    const int key = clampL(kstart + row);
    const float* src = kg + ((size_t)(b * L_ + key) * H_ + h) * E_ + chs * 4;
    float* dst = &Ks32[(it * 256 + wave * 64) * 4];   // wave-uniform base; HW adds lane*16
    __builtin_amdgcn_global_load_lds(
        (__attribute__((address_space(1))) void*)src,
        (__attribute__((address_space(3))) void*)dst, 16, 0, 0);
  }

  // ---- V pack -> Vt (bf16 transposed), zero-pad key cols 128..143 ----
  #pragma unroll
  for (int i = 0; i < 4; ++i)
    #pragma unroll
    for (int j = 0; j < 4; ++j) {
      int d = dq * 16 + i * 4 + j;
      *(unsigned int*)&Vt[d * VT_STRIDE + 2 * kp] = pack2(va[i][j], vc[i][j]);
    }
  *(uint2*)&Vt[(t >> 2) * VT_STRIDE + 128 + (t & 3) * 4] = make_uint2(0u, 0u);

  const short8 qa0 = pack8(qf0, qf1);
  const short8 qa1 = pack8(qf2, qf3);

  __syncthreads();   // the ONLY barrier; drains gload_lds + ds_writes

  // ---- QK swapped: acc = S^T tile. A = K-frag from Ks32 (swizzled chunks).
  //      Lane holds S[key = wave*16 + tt*16 + quad*4 + r][query = col16].
  //      krow & 15 == col16, so the read-side XOR is just ^col16. ----
  const int c0 = (2 * quad) ^ col16;        // chunk of dims quad*8..+3
  const int c1 = (2 * quad + 1) ^ col16;    // dims quad*8+4..+7
  const int c2 = (2 * quad + 8) ^ col16;    // dims 32+quad*8..+3
  const int c3 = (2 * quad + 9) ^ col16;    // dims 32+quad*8+4..+7
  f32x4 acc[5];
  #pragma unroll
  for (int tt = 0; tt < 5; ++tt) {
    const int krow = wave * 16 + tt * 16 + col16;
    const float* Kr = &Ks32[krow * 64];
    f32x4 k0 = *(const f32x4*)(Kr + c0 * 4);
    f32x4 k1 = *(const f32x4*)(Kr + c1 * 4);
    f32x4 k2 = *(const f32x4*)(Kr + c2 * 4);
    f32x4 k3 = *(const f32x4*)(Kr + c3 * 4);
    short8 kb0 = pack8(k0, k1);
    short8 kb1 = pack8(k2, k3);
    f32x4 c = {0.f, 0.f, 0.f, 0.f};
    c = __builtin_amdgcn_mfma_f32_16x16x32_bf16(kb0, qa0, c, 0, 0, 0);
    c = __builtin_amdgcn_mfma_f32_16x16x32_bf16(kb1, qa1, c, 0, 0, 0);
    acc[tt] = c;
  }

  // ---- Mask + softmax. Query = col16 (fixed per lane); keys over (tt,quad,r).
  //      Cross-lane reduce = quads only: shfl_xor 16, 32. ----
  float mx = -1e30f;
  #pragma unroll
  for (int tt = 0; tt < 5; ++tt)
    #pragma unroll
    for (int r = 0; r < 4; ++r) {
      const int k_loc = tt * 16 + quad * 4 + r;          // key rel to wave band
      const int gkey = kstart + wave * 16 + k_loc;       // global key
      const bool ok = (k_loc >= col16) && (k_loc < col16 + 64) &&
                      (gkey >= 0) && (gkey < L_);
      const float v = ok ? acc[tt][r] * 0.125f : -1e30f; // scale = 1/sqrt(64)
      acc[tt][r] = v;
      mx = fmaxf(mx, v);
    }
  mx = fmaxf(mx, __shfl_xor(mx, 16));
  mx = fmaxf(mx, __shfl_xor(mx, 32));
  float s = 0.f;
  #pragma unroll
  for (int tt = 0; tt < 5; ++tt)
    #pragma unroll
    for (int r = 0; r < 4; ++r) {
      const float e = __expf(acc[tt][r] - mx);
      acc[tt][r] = e;
      s += e;
    }
  s += __shfl_xor(s, 16);
  s += __shfl_xor(s, 32);
  const float inv = 1.0f / s;          // >= 32 valid keys -> s >= 1

  // ---- P -> PV A-frags IN REGISTER (lane-local by construction).
  //      elem j of pa[ks] = P[col16][32ks+16(j>>2)+4quad+(j&3)]
  //      = acc[2ks + (j>>2)][j&3]. Tail frag: elems 4..7 = 0. ----
  short8 pa[3];
  {
    union { short8 s8; uint4 u4; } w;
    w.u4 = make_uint4(pack2(acc[0][0] * inv, acc[0][1] * inv),
                      pack2(acc[0][2] * inv, acc[0][3] * inv),
                      pack2(acc[1][0] * inv, acc[1][1] * inv),
                      pack2(acc[1][2] * inv, acc[1][3] * inv));
    pa[0] = w.s8;
    w.u4 = make_uint4(pack2(acc[2][0] * inv, acc[2][1] * inv),
                      pack2(acc[2][2] * inv, acc[2][3] * inv),
                      pack2(acc[3][0] * inv, acc[3][1] * inv),
                      pack2(acc[3][2] * inv, acc[3][3] * inv));
    pa[1] = w.s8;
    w.u4 = make_uint4(pack2(acc[4][0] * inv, acc[4][1] * inv),
                      pack2(acc[4][2] * inv, acc[4][3] * inv), 0u, 0u);
    pa[2] = w.s8;
  }

  // ---- PV: per dim-tile nt, 3 K=32 steps. B elem j = V[key(quad*8+j)][dim]:
  //      two uint2 (4 consecutive keys each) at cols base+quad*4 and +16. ----
  f32x4 oacc[4];
  #pragma unroll
  for (int nt = 0; nt < 4; ++nt) oacc[nt] = (f32x4){0.f, 0.f, 0.f, 0.f};
  #pragma unroll
  for (int nt = 0; nt < 4; ++nt) {
    const int rowb = (nt * 16 + col16) * VT_STRIDE;
    #pragma unroll
    for (int ks = 0; ks < 3; ++ks) {
      union { short8 s8; uint2 u2[2]; } vb;
      vb.u2[0] = *(const uint2*)&Vt[rowb + wave * 16 + ks * 32 + quad * 4];
      vb.u2[1] = *(const uint2*)&Vt[rowb + wave * 16 + ks * 32 + 16 + quad * 4];
      oacc[nt] = __builtin_amdgcn_mfma_f32_16x16x32_bf16(pa[ks], vb.s8, oacc[nt], 0, 0, 0);
    }
  }

  // ---- Store O (fp32). C: row = quad*4+r (query), col = col16 (dim) ----
  #pragma unroll
  for (int r = 0; r < 4; ++r) {
    const int q = q0 + wave * 16 + quad * 4 + r;
    float* orow = og + ((size_t)(b * L_ + q) * H_ + h) * D_;
    #pragma unroll
    for (int nt = 0; nt < 4; ++nt)
      orow[nt * 16 + col16] = oacc[nt][r];
  }
}

extern "C" void kernel_launch(void* const* d_in, const int* in_sizes, int n_in,
                              void* d_out, int out_size, void* d_ws, size_t ws_size,
                              hipStream_t stream) {
  const float* q = (const float*)d_in[0];
  const float* k = (const float*)d_in[1];
  const float* v = (const float*)d_in[2];
  float* o = (float*)d_out;
  dim3 grid(L_ / 64, H_, B_);
  local_attn_mfma<<<grid, dim3(256), 0, stream>>>(q, k, v, o);
}